// Round 10
// baseline (6190.026 us; speedup 1.0000x reference)
//
#include <hip/hip_runtime.h>
#include <hip/hip_bf16.h>

typedef __attribute__((ext_vector_type(8))) short bf16x8;
typedef __attribute__((ext_vector_type(4))) float f32x4;

#define HID 1024
#define BATCH 32
#define NACT (BATCH * HID)        // 32768
#define NWIH (3 * 3 * HID * HID)  // 9,437,184  plane stride (all layers)
#define LSTRIDE (3 * HID * HID)   // per-layer offset within a plane
#define NFC (2500 * HID)          // 2,560,000
#define WXN (HID * HID)           // 1,048,576
#define WXIN (3 * HID * HID)      // 3,145,728 (3072x1024)
#define G3 (3 * HID)              // 3072
#define NGI (32 * G3)             // 98,304 floats per GI part
#define NGH (3 * 32 * G3)         // 294,912 floats per GH part
#define TSTEPS 64
#define NBLK 512
#define NTHR 512
#define FSTRIDE 32

__device__ __forceinline__ f32x4 mfma16(bf16x8 a, bf16x8 b, f32x4 c) {
  return __builtin_amdgcn_mfma_f32_16x16x32_bf16(a, b, c, 0, 0, 0);
}
__device__ __forceinline__ float bfbits2f(unsigned short u) {
  return __uint_as_float(((unsigned int)u) << 16);
}
__device__ __forceinline__ unsigned short f2bf_rn(float v) {
  union { __hip_bfloat16 b; unsigned short s; } cv;
  cv.b = __float2bfloat16(v);
  return cv.s;
}
// exact 3-way split of fp32: 8+8+8 mantissa bits (trunc, trunc, RN)
__device__ __forceinline__ void split3(float v, unsigned short& s0, unsigned short& s1,
                                       unsigned short& s2) {
  s0 = (unsigned short)(__float_as_uint(v) >> 16);
  float r1 = v - bfbits2f(s0);
  s1 = (unsigned short)(__float_as_uint(r1) >> 16);
  float r2 = r1 - bfbits2f(s1);
  s2 = f2bf_rn(r2);
}
__device__ __forceinline__ void split2(float v, unsigned short& s0, unsigned short& s1) {
  s0 = (unsigned short)(__float_as_uint(v) >> 16);
  s1 = f2bf_rn(v - bfbits2f(s0));
}
// coherent (agent/MALL) 16B activation load as 2x 8B relaxed atomics
__device__ __forceinline__ bf16x8 ld_act16(const unsigned short* p) {
  union { unsigned long long u[2]; bf16x8 v; } cv;
  cv.u[0] = __hip_atomic_load((unsigned long long*)p, __ATOMIC_RELAXED, __HIP_MEMORY_SCOPE_AGENT);
  cv.u[1] = __hip_atomic_load((unsigned long long*)p + 1, __ATOMIC_RELAXED, __HIP_MEMORY_SCOPE_AGENT);
  return cv.v;
}
__device__ __forceinline__ float ld_f32(const float* p) {
  return __hip_atomic_load(p, __ATOMIC_RELAXED, __HIP_MEMORY_SCOPE_AGENT);
}
__device__ __forceinline__ void st_f32(float* p, float v) {
  __hip_atomic_store(p, v, __ATOMIC_RELAXED, __HIP_MEMORY_SCOPE_AGENT);
}
// paired-lane packed plane store: (even,odd) lanes pack adjacent j's into one u32
__device__ __forceinline__ void pst_plane(unsigned short* plane, int eidx, unsigned short s,
                                          int par) {
  int other = __shfl_xor((int)(unsigned int)s, 1, 64);
  unsigned int packed = ((unsigned int)s) | (((unsigned int)(unsigned short)other) << 16);
  if (!par)
    __hip_atomic_store((unsigned int*)(plane + eidx), packed, __ATOMIC_RELAXED,
                       __HIP_MEMORY_SCOPE_AGENT);
}

// ---------------- one-time kernels ----------------
__global__ void convert_weights(const float* __restrict__ Wih, const float* __restrict__ Whh,
                                unsigned short* __restrict__ WIHP, unsigned short* __restrict__ WHHP) {
  int i0 = blockIdx.x * blockDim.x + threadIdx.x;
  int st = gridDim.x * blockDim.x;
  for (int i = i0; i < NWIH; i += st) {
    unsigned short a0, a1, b0, b1;
    split2(Wih[i], a0, a1);
    split2(Whh[i], b0, b1);
    WIHP[i] = a0; WIHP[NWIH + i] = a1;
    WHHP[i] = b0; WHHP[NWIH + i] = b1;
  }
}

__global__ void convert_fcw(const float* __restrict__ fcw, unsigned short* __restrict__ FCWP) {
  int i0 = blockIdx.x * blockDim.x + threadIdx.x;
  int st = gridDim.x * blockDim.x;
  for (int i = i0; i < NFC; i += st) {
    unsigned short c0, c1;
    split2(fcw[i], c0, c1);
    FCWP[i] = c0; FCWP[NFC + i] = c1;
  }
}

__global__ void k_trig(float* __restrict__ cA, float* __restrict__ sA) {
  int i = blockIdx.x * blockDim.x + threadIdx.x;
  if (i < 32 * 50) {
    int a = i / 50, n = i % 50;
    int ka = (a + 34) % 50;  // fftshift+crop row map
    int ph = (ka * n) % 50;  // exact integer angle reduction
    float ang = 6.283185307179586f * (float)ph / 50.0f;
    cA[i] = cosf(ang);
    sA[i] = sinf(ang);
  }
}

// P[(n1*32+c)*256 + kk] for h-chunk [k0,k0+256)
__global__ void k_pq(const float* __restrict__ fcw, const float* __restrict__ cA,
                     const float* __restrict__ sA, float* __restrict__ P, float* __restrict__ Q,
                     int k0) {
  int n1 = blockIdx.x;
  int kk = threadIdx.x;
  int k = k0 + kk;
  float accP[32], accQ[32];
#pragma unroll
  for (int c = 0; c < 32; ++c) { accP[c] = 0.f; accQ[c] = 0.f; }
  for (int n2 = 0; n2 < 50; ++n2) {
    float w = fcw[(n1 * 50 + n2) * HID + k];
#pragma unroll
    for (int c = 0; c < 32; ++c) {
      accP[c] = fmaf(w, cA[c * 50 + n2], accP[c]);
      accQ[c] = fmaf(w, sA[c * 50 + n2], accQ[c]);
    }
  }
#pragma unroll
  for (int c = 0; c < 32; ++c) {
    P[(n1 * 32 + c) * 256 + kk] = accP[c];
    Q[(n1 * 32 + c) * 256 + kk] = accQ[c];
  }
}

// WxF[f][h] fp32 for h-chunk
__global__ void k_wx(const float* __restrict__ P, const float* __restrict__ Q,
                     const float* __restrict__ cA, const float* __restrict__ sA,
                     float* __restrict__ WxF, int k0) {
  int j = blockIdx.x;  // x feature f
  int a = j >> 5, c = j & 31;
  int kk = threadIdx.x;
  float acc = 0.f;
  for (int n1 = 0; n1 < 50; ++n1) {
    int base = (n1 * 32 + c) * 256 + kk;
    acc = fmaf(cA[a * 50 + n1], P[base], acc);
    acc = fmaf(-sA[a * 50 + n1], Q[base], acc);
  }
  WxF[j * HID + k0 + kk] = acc;
}

// transpose WxF[f][h] -> WXTP planes [h][f] (3-plane exact)
__global__ void k_transpose(const float* __restrict__ WxF, unsigned short* __restrict__ WXTP) {
  __shared__ float lds[64][65];
  int f0 = blockIdx.x * 64, h0 = blockIdx.y * 64;
  for (int idx = threadIdx.x; idx < 4096; idx += 256) {
    int r = idx >> 6, c = idx & 63;
    lds[r][c] = WxF[(f0 + r) * HID + h0 + c];
  }
  __syncthreads();
  for (int idx = threadIdx.x; idx < 4096; idx += 256) {
    int r = idx >> 6, c = idx & 63;  // r = h-local, c = f-local
    unsigned short s0, s1, s2;
    split3(lds[c][r], s0, s1, s2);
    int o = (h0 + r) * HID + f0 + c;
    WXTP[o] = s0; WXTP[WXN + o] = s1; WXTP[2 * WXN + o] = s2;
  }
}

// compose: WXI[g][h] = sum_f Wih0[g][f] * Wx[f][h]; Wih0 2-plane, Wx 3-plane, out 2-plane
__global__ __launch_bounds__(256) void k_compose(const unsigned short* __restrict__ WIHP,
                                                 const unsigned short* __restrict__ WXTP,
                                                 unsigned short* __restrict__ WXIP) {
  int tid = threadIdx.x;
  int L = tid & 63, ws = tid >> 6;
  int col = L & 15, quad = L >> 4;
  int m0 = blockIdx.y * 64 + ws * 16;  // g strip
  int jt = blockIdx.x * 64;            // h tile
  f32x4 acc[4];
#pragma unroll
  for (int s = 0; s < 4; ++s) acc[s] = {0.f, 0.f, 0.f, 0.f};
  for (int kt = 0; kt < 32; ++kt) {
    int k0 = kt * 32 + quad * 8;
    bf16x8 a[2], b[3][4];
#pragma unroll
    for (int q = 0; q < 2; ++q)
      a[q] = *(const bf16x8*)(WIHP + (size_t)q * NWIH + (m0 + col) * HID + k0);
#pragma unroll
    for (int s = 0; s < 4; ++s)
#pragma unroll
      for (int p = 0; p < 3; ++p)
        b[p][s] = *(const bf16x8*)(WXTP + (size_t)p * WXN + (jt + s * 16 + col) * HID + k0);
#pragma unroll
    for (int p = 0; p < 3; ++p)
#pragma unroll
      for (int q = 0; q < 2; ++q)
        if (p + q <= 2)
#pragma unroll
          for (int s = 0; s < 4; ++s) acc[s] = mfma16(a[q], b[p][s], acc[s]);
  }
#pragma unroll
  for (int s = 0; s < 4; ++s) {
    int h = jt + s * 16 + col;
#pragma unroll
    for (int r = 0; r < 4; ++r) {
      int g = m0 + quad * 4 + r;
      unsigned short s0, s1;
      split2(acc[s][r], s0, s1);
      WXIP[(size_t)g * HID + h] = s0;
      WXIP[(size_t)WXIN + (size_t)g * HID + h] = s1;
    }
  }
}

__global__ void k_cx(const float* __restrict__ fcb, const float* __restrict__ cA,
                     const float* __restrict__ sA, float* __restrict__ CXV) {
  int j = blockIdx.x * blockDim.x + threadIdx.x;
  if (j >= HID) return;
  int a = j >> 5, c = j & 31;
  float acc = 0.f;
  for (int n1 = 0; n1 < 50; ++n1)
    for (int n2 = 0; n2 < 50; ++n2)
      acc += fcb[n1 * 50 + n2] * (cA[a * 50 + n1] * cA[c * 50 + n2] - sA[a * 50 + n1] * sA[c * 50 + n2]);
  CXV[j] = acc;
}

// BIH0C[g] = b_ih0[g] + sum_k CXV[k] * Wih0[g][k]
__global__ void k_bih0c(const float* __restrict__ b_ih, const float* __restrict__ CXV,
                        const float* __restrict__ Wih, float* __restrict__ BIH0C) {
  __shared__ float red[256];
  int g = blockIdx.x;
  float p = 0.f;
  for (int k = threadIdx.x; k < HID; k += 256) p = fmaf(CXV[k], Wih[(size_t)g * HID + k], p);
  red[threadIdx.x] = p;
  __syncthreads();
  for (int s = 128; s > 0; s >>= 1) {
    if (threadIdx.x < s) red[threadIdx.x] += red[threadIdx.x + s];
    __syncthreads();
  }
  if (threadIdx.x == 0) BIH0C[g] = b_ih[g] + red[0];
}

__global__ void setup_state(const float* __restrict__ x_in, float* __restrict__ H,
                            unsigned short* __restrict__ HBP, unsigned short* __restrict__ XBP,
                            unsigned int* __restrict__ flags, unsigned int* __restrict__ rel) {
  int i0 = blockIdx.x * blockDim.x + threadIdx.x;
  int st = gridDim.x * blockDim.x;
  for (int k = i0; k < NBLK * FSTRIDE; k += st) flags[k] = 0u;
  if (i0 == 0) *rel = 0u;
  for (int k = i0; k < 3 * NACT; k += st) H[k] = 0.0f;
  for (int k = i0; k < 3 * 3 * NACT; k += st) HBP[k] = 0;
  for (int k = i0; k < NACT; k += st) {
    unsigned short s0, s1, s2;
    split3(x_in[k], s0, s1, s2);
    XBP[k] = s0; XBP[NACT + k] = s1; XBP[2 * NACT + k] = s2;
  }
}

// ---------------- grid barrier: parallel flags + master gather + release ----------------
__device__ __forceinline__ void gbar(unsigned int* flags, unsigned int* rel, unsigned int e) {
  __syncthreads();
  const int tid = threadIdx.x;
  const int bid = blockIdx.x;
  if (tid == 0)
    __hip_atomic_store(flags + bid * FSTRIDE, e, __ATOMIC_RELAXED, __HIP_MEMORY_SCOPE_AGENT);
  if (bid == 0) {
    if (tid < 64) {
      for (;;) {
        bool ok = true;
#pragma unroll
        for (int i = 0; i < 8; ++i) {
          unsigned int v = __hip_atomic_load(flags + (tid + 64 * i) * FSTRIDE, __ATOMIC_RELAXED,
                                             __HIP_MEMORY_SCOPE_AGENT);
          ok &= (v >= e);
        }
        if (__all(ok)) break;
        __builtin_amdgcn_s_sleep(1);
      }
      if (tid == 0) __hip_atomic_store(rel, e, __ATOMIC_RELAXED, __HIP_MEMORY_SCOPE_AGENT);
    }
  } else if (tid == 0) {
    while (__hip_atomic_load(rel, __ATOMIC_RELAXED, __HIP_MEMORY_SCOPE_AGENT) < e)
      __builtin_amdgcn_s_sleep(1);
  }
  __syncthreads();
}

// ---------------- GEMM half-K tile: 32(batch) x NT*16(features), K=512 over 8 waves ----------
// act 3-plane (stride NACT), weights 2-plane (stride bplane), plane pairs p+q<=2 (5 pairs).
template <int NT>
__device__ __forceinline__ void gemm_half(const unsigned short* __restrict__ Bp, size_t bplane,
                                          const unsigned short* __restrict__ Ap, int gfbase,
                                          int koff, float* smem, f32x4 (&acc)[NT][2]) {
  const int tid = threadIdx.x;
  const int L = tid & 63, w = tid >> 6;
  const int col = L & 15, quad = L >> 4;
#pragma unroll
  for (int n = 0; n < NT; ++n) {
    acc[n][0] = {0.f, 0.f, 0.f, 0.f};
    acc[n][1] = {0.f, 0.f, 0.f, 0.f};
  }
#pragma unroll
  for (int it = 0; it < 2; ++it) {
    int k0 = koff + w * 64 + it * 32 + quad * 8;
    bf16x8 a[3][2], b[2][NT];
#pragma unroll
    for (int mh = 0; mh < 2; ++mh) {
      int r = (mh * 16 + col) * HID + k0;
#pragma unroll
      for (int q = 0; q < 3; ++q) a[q][mh] = ld_act16(Ap + (size_t)q * NACT + r);
    }
#pragma unroll
    for (int n = 0; n < NT; ++n) {
      int rr = (gfbase + n * 16 + col) * HID + k0;
#pragma unroll
      for (int p = 0; p < 2; ++p) b[p][n] = *(const bf16x8*)(Bp + (size_t)p * bplane + rr);
    }
#pragma unroll
    for (int p = 0; p < 2; ++p)
#pragma unroll
      for (int q = 0; q < 3; ++q)
        if (p + q <= 2)
#pragma unroll
          for (int n = 0; n < NT; ++n)
#pragma unroll
            for (int mh = 0; mh < 2; ++mh) acc[n][mh] = mfma16(a[q][mh], b[p][n], acc[n][mh]);
  }
  __syncthreads();
  if (w > 0) {
    float* s = smem + ((w - 1) * 64 + L) * (NT * 8);
#pragma unroll
    for (int n = 0; n < NT; ++n) {
      *(f32x4*)(s + n * 8) = acc[n][0];
      *(f32x4*)(s + n * 8 + 4) = acc[n][1];
    }
  }
  __syncthreads();
  if (w == 0) {
#pragma unroll
    for (int sx = 0; sx < 7; ++sx) {
      const float* p = smem + (sx * 64 + L) * (NT * 8);
#pragma unroll
      for (int n = 0; n < NT; ++n) {
        acc[n][0] += *(const f32x4*)(p + n * 8);
        acc[n][1] += *(const f32x4*)(p + n * 8 + 4);
      }
    }
  }
}

// gi0 for t=0 from input x (XBP planes): 384 blocks, K-split x2
__global__ __launch_bounds__(NTHR, 4) void gi0_first(const unsigned short* __restrict__ WIHP,
                                                     const unsigned short* __restrict__ XBP,
                                                     float* __restrict__ GI) {
  __shared__ float smem[3584];
  const int tid = threadIdx.x;
  const int L = tid & 63, w = tid >> 6;
  const int col = L & 15, quad = L >> 4;
  int part = blockIdx.x & 1, tile = blockIdx.x >> 1;
  int gf = tile * 16;
  f32x4 acc[1][2];
  gemm_half<1>(WIHP, NWIH, XBP, gf, part * 512, smem, acc);
  if (w == 0) {
    float* outp = GI + (size_t)part * NGI;
#pragma unroll
    for (int mh = 0; mh < 2; ++mh)
#pragma unroll
      for (int r = 0; r < 4; ++r) {
        int b = mh * 16 + quad * 4 + r;
        st_f32(outp + (size_t)b * G3 + gf + col, acc[0][mh][r]);
      }
  }
}

// ---------------- persistent kernel: 64 x (A, P0, G1, P1, G2, P2) ----------------
// __launch_bounds__(512, 4): min 4 waves/EU -> VGPR cap 128 -> 2 blocks/CU guaranteed
// co-resident for the 512-block persistent grid (deadlock-free barrier).
__global__ __launch_bounds__(NTHR, 4) void rnn_persistent(
    const unsigned short* __restrict__ WIHP, const unsigned short* __restrict__ WHHP,
    const unsigned short* __restrict__ WXIP,
    const float* __restrict__ b_ih, const float* __restrict__ b_hh,
    const float* __restrict__ BIH0C,
    float* __restrict__ H,             // [3][NACT] fp32
    unsigned short* __restrict__ HBP,  // [3 layers][3 planes][NACT]
    float* __restrict__ GH,            // [2 parts][3][32][3072]
    float* __restrict__ GI,            // [2 parts][32][3072]
    unsigned short* __restrict__ HIST0, unsigned short* __restrict__ HIST1,  // [2048][1024]
    unsigned int* __restrict__ FLAGS, unsigned int* __restrict__ REL) {
  __shared__ float smem[10752];
  const int tid = threadIdx.x;
  const int L = tid & 63, w = tid >> 6;
  const int col = L & 15, quad = L >> 4;
  const int bid = blockIdx.x;
  unsigned int ep = 0;

#pragma unroll 1
  for (int t = 0; t < TSTEPS; ++t) {
    // ===== Phase A: gh0,gh1,gh2 (vs h_{t-1}) + composed gi0 (vs h2_{t-1}); NT=3, K-split x2 =====
    {
      int part = bid & 1;
      int task = bid >> 1;  // 0..255
      int koff = part * 512;
      if (task < 192) {
        int s = task >> 6;
        int gf = (task & 63) * 48;
        f32x4 acc[3][2];
        gemm_half<3>(WHHP + (size_t)s * LSTRIDE, NWIH, HBP + (size_t)s * 3 * NACT, gf, koff,
                     smem, acc);
        if (w == 0) {
          float* outp = GH + (size_t)part * NGH + (size_t)s * (32 * G3);
#pragma unroll
          for (int n = 0; n < 3; ++n)
#pragma unroll
            for (int mh = 0; mh < 2; ++mh)
#pragma unroll
              for (int r = 0; r < 4; ++r) {
                int b = mh * 16 + quad * 4 + r;
                st_f32(outp + (size_t)b * G3 + gf + n * 16 + col, acc[n][mh][r]);
              }
        }
      } else if (t > 0) {  // t==0: gi0 precomputed by gi0_first
        int gf = (task - 192) * 48;
        f32x4 acc[3][2];
        gemm_half<3>(WXIP, WXIN, HBP + (size_t)2 * 3 * NACT, gf, koff, smem, acc);
        if (w == 0) {
          float* outp = GI + (size_t)part * NGI;
#pragma unroll
          for (int n = 0; n < 3; ++n)
#pragma unroll
            for (int mh = 0; mh < 2; ++mh)
#pragma unroll
              for (int r = 0; r < 4; ++r) {
                int b = mh * 16 + quad * 4 + r;
                st_f32(outp + (size_t)b * G3 + gf + n * 16 + col, acc[n][mh][r]);
              }
        }
      }
    }
    gbar(FLAGS, REL, ++ep);

#pragma unroll 1
    for (int l = 0; l < 3; ++l) {
      // ---- pointwise layer l (64 blocks, 1 elem/thread; adds the two K-halves) ----
      if (bid < 64) {
        int jt = bid * 16;
        int b = tid >> 4, jj = tid & 15, j = jt + jj;
        const float* bi_base = (l == 0) ? ((t == 0) ? b_ih : BIH0C) : (b_ih + l * G3);
        const float* bh_base = b_hh + l * G3;
        float gi[3], gh[3];
#pragma unroll
        for (int g = 0; g < 3; ++g) {
          size_t off = (size_t)b * G3 + g * HID + j;
          gi[g] = ld_f32(GI + off) + ld_f32(GI + NGI + off);
          size_t offh = (size_t)l * (32 * G3) + off;
          gh[g] = ld_f32(GH + offh) + ld_f32(GH + NGH + offh);
        }
        float ir = gi[0] + bi_base[j];
        float iz = gi[1] + bi_base[HID + j];
        float in_ = gi[2] + bi_base[2 * HID + j];
        float hr = gh[0] + bh_base[j];
        float hz = gh[1] + bh_base[HID + j];
        float hn = gh[2] + bh_base[2 * HID + j];
        float rr = 1.0f / (1.0f + expf(-(ir + hr)));
        float zz = 1.0f / (1.0f + expf(-(iz + hz)));
        float nn = tanhf(in_ + rr * hn);
        float hold = H[(size_t)l * NACT + b * HID + j];
        float hnew = (1.0f - zz) * nn + zz * hold;
        H[(size_t)l * NACT + b * HID + j] = hnew;
        unsigned short s0, s1, s2;
        split3(hnew, s0, s1, s2);
        int eidx = b * HID + j;
        unsigned short* hb = HBP + (size_t)l * 3 * NACT;
        int par = tid & 1;
        pst_plane(hb, eidx, s0, par);
        pst_plane(hb + NACT, eidx, s1, par);
        pst_plane(hb + 2 * NACT, eidx, s2, par);
        if (l == 2) {
          HIST0[(size_t)(t * BATCH + b) * HID + j] = s0;
          HIST1[(size_t)(t * BATCH + b) * HID + j] = s1;
        }
      }
      gbar(FLAGS, REL, ++ep);

      // ---- gi for layer l+1 (384 blocks: 192 tiles x 2 K-halves) ----
      if (l < 2) {
        if (bid < 384) {
          int part = bid & 1, tile = bid >> 1;
          int gf = tile * 16;
          f32x4 acc[1][2];
          gemm_half<1>(WIHP + (size_t)(l + 1) * LSTRIDE, NWIH, HBP + (size_t)l * 3 * NACT, gf,
                       part * 512, smem, acc);
          if (w == 0) {
            float* outp = GI + (size_t)part * NGI;
#pragma unroll
            for (int mh = 0; mh < 2; ++mh)
#pragma unroll
              for (int r = 0; r < 4; ++r) {
                int b = mh * 16 + quad * 4 + r;
                st_f32(outp + (size_t)b * G3 + gf + col, acc[0][mh][r]);
              }
          }
        }
        gbar(FLAGS, REL, ++ep);
      }
    }
  }
}

// ---------------- deferred output GEMM: dout[2048][2500] = HIST(2pl) @ FCW(2pl)^T + fcb ------
__global__ __launch_bounds__(256) void final_fc(const unsigned short* __restrict__ H0,
                                                const unsigned short* __restrict__ H1,
                                                const unsigned short* __restrict__ FCWP,
                                                const float* __restrict__ fcb,
                                                float* __restrict__ dout) {
  int tid = threadIdx.x;
  int L = tid & 63, ws = tid >> 6;
  int col = L & 15, quad = L >> 4;
  int m0 = blockIdx.y * 64 + ws * 16;
  int jt = blockIdx.x * 64;
  f32x4 acc[4];
#pragma unroll
  for (int s = 0; s < 4; ++s) acc[s] = {0.f, 0.f, 0.f, 0.f};
  for (int kt = 0; kt < 32; ++kt) {
    int k0 = kt * 32 + quad * 8;
    bf16x8 ah = *(const bf16x8*)(H0 + (size_t)(m0 + col) * HID + k0);
    bf16x8 am = *(const bf16x8*)(H1 + (size_t)(m0 + col) * HID + k0);
    bf16x8 bh[4], bm[4];
#pragma unroll
    for (int s = 0; s < 4; ++s) {
      int jr = jt + s * 16 + col;
      int rc = jr < 2500 ? jr : 2499;
      bh[s] = *(const bf16x8*)(FCWP + (size_t)rc * HID + k0);
      bm[s] = *(const bf16x8*)(FCWP + (size_t)NFC + (size_t)rc * HID + k0);
    }
#pragma unroll
    for (int s = 0; s < 4; ++s) {
      acc[s] = mfma16(ah, bh[s], acc[s]);
      acc[s] = mfma16(ah, bm[s], acc[s]);
      acc[s] = mfma16(am, bh[s], acc[s]);
    }
  }
#pragma unroll
  for (int s = 0; s < 4; ++s) {
    int j = jt + s * 16 + col;
    if (j < 2500) {
      float bias = fcb[j];
#pragma unroll
      for (int r = 0; r < 4; ++r) {
        int R = m0 + quad * 4 + r;
        dout[(size_t)R * 2500 + j] = acc[s][r] + bias;
      }
    }
  }
}

extern "C" void kernel_launch(void* const* d_in, const int* in_sizes, int n_in,
                              void* d_out, int out_size, void* d_ws, size_t ws_size,
                              hipStream_t stream) {
  const float* x_in = (const float*)d_in[0];
  const float* W_ih = (const float*)d_in[1];
  const float* W_hh = (const float*)d_in[2];
  const float* b_ih = (const float*)d_in[3];
  const float* b_hh = (const float*)d_in[4];
  const float* fc_w = (const float*)d_in[5];
  const float* fc_b = (const float*)d_in[6];
  float* dout = (float*)d_out;
  char* ws = (char*)d_ws;

  // ---- workspace layout (bytes), region reuse across disjoint lifetimes ----
  unsigned short* WIHP = (unsigned short*)(ws + 0);            // 37,748,736 (2 planes)
  unsigned short* WHHP = (unsigned short*)(ws + 37748736);     // 37,748,736 -> 75,497,472
  // region C: WXIP (persistent) then FCWP (post-loop alias)
  unsigned short* WXIP = (unsigned short*)(ws + 75497472);     // 12,582,912 -> 88,080,384
  unsigned short* FCWP = (unsigned short*)(ws + 75497472);     // 10,240,000 (alias, post-loop)
  // region D: setup scratch (PQ + WxF + WXTP) then HIST0/1
  float* Pbuf          = (float*)(ws + 88080384);              // 1,638,400
  float* Qbuf          = (float*)(ws + 89718784);              // 1,638,400
  float* WxF           = (float*)(ws + 91357184);              // 4,194,304
  unsigned short* WXTP = (unsigned short*)(ws + 95551488);     // 6,291,456 -> 101,842,944
  unsigned short* HIST0 = (unsigned short*)(ws + 88080384);    // 4,194,304 (alias)
  unsigned short* HIST1 = (unsigned short*)(ws + 92274688);    // 4,194,304 (alias)
  // state block
  float* H             = (float*)(ws + 101842944);             // 393,216
  unsigned short* HBP  = (unsigned short*)(ws + 102236160);    // 589,824
  unsigned short* XBP  = (unsigned short*)(ws + 102825984);    // 196,608
  float* GH            = (float*)(ws + 103022592);             // 2,359,296 (2 parts)
  float* GI            = (float*)(ws + 105381888);             // 786,432 (2 parts)
  float* CXV           = (float*)(ws + 106168320);             // 4,096
  float* CA            = (float*)(ws + 106172416);             // 6,400
  float* SA            = (float*)(ws + 106178816);             // 6,400
  float* BIH0C         = (float*)(ws + 106185216);             // 12,288
  unsigned int* FLAGS  = (unsigned int*)(ws + 106197504);      // 65,536 (512 x 128B)
  unsigned int* REL    = (unsigned int*)(ws + 106263040);      // 128 -> end 106,263,168

  k_trig<<<7, 256, 0, stream>>>(CA, SA);
  for (int k0 = 0; k0 < 1024; k0 += 256) {
    k_pq<<<50, 256, 0, stream>>>(fc_w, CA, SA, Pbuf, Qbuf, k0);
    k_wx<<<1024, 256, 0, stream>>>(Pbuf, Qbuf, CA, SA, WxF, k0);
  }
  k_transpose<<<dim3(16, 16), 256, 0, stream>>>(WxF, WXTP);
  convert_weights<<<2048, 256, 0, stream>>>(W_ih, W_hh, WIHP, WHHP);
  k_compose<<<dim3(16, 48), 256, 0, stream>>>(WIHP, WXTP, WXIP);
  k_cx<<<4, 256, 0, stream>>>(fc_b, CA, SA, CXV);
  k_bih0c<<<3072, 256, 0, stream>>>(b_ih, CXV, W_ih, BIH0C);
  setup_state<<<512, 256, 0, stream>>>(x_in, H, HBP, XBP, FLAGS, REL);
  gi0_first<<<384, NTHR, 0, stream>>>(WIHP, XBP, GI);
  rnn_persistent<<<NBLK, NTHR, 0, stream>>>(WIHP, WHHP, WXIP, b_ih, b_hh, BIH0C, H, HBP,
                                            GH, GI, HIST0, HIST1, FLAGS, REL);
  convert_fcw<<<1024, 256, 0, stream>>>(fc_w, FCWP);
  final_fc<<<dim3(40, 32), 256, 0, stream>>>(HIST0, HIST1, FCWP, fc_b, dout);
}